// Round 7
// baseline (112.762 us; speedup 1.0000x reference)
//
#include <hip/hip_runtime.h>
#include <hip/hip_bf16.h>
#include <stdint.h>

// Problem constants: N=4096, T=16, D=700 (pad 704), C=128, NC=20
// Output layout (f32): out0 [4096,20] | features [16,4096,128] | attended [16,4096,128]

typedef __attribute__((ext_vector_type(8))) short short8;    // bf16x8 MFMA frag
typedef __attribute__((ext_vector_type(4))) float f32x4;
typedef __attribute__((ext_vector_type(16))) float f32x16;   // 32x32 acc
typedef unsigned long long u64;

#define MFMA32(a, b, c) __builtin_amdgcn_mfma_f32_32x32x16_bf16(a, b, c, 0, 0, 0)

__device__ inline void gload16(const void* g, void* l) {
  __builtin_amdgcn_global_load_lds(
      (const __attribute__((address_space(1))) uint32_t*)g,
      (__attribute__((address_space(3))) uint32_t*)l, 16, 0, 0);
}

// Exact 3-way bf16 split (scalar, prep kernel)
__device__ inline float bf_round(float v, short& bits) {
  __hip_bfloat16 b = __float2bfloat16(v);
  short s; __builtin_memcpy(&s, &b, 2);
  bits = s;
  unsigned int u = ((unsigned int)(unsigned short)s) << 16;
  return __uint_as_float(u);
}
__device__ inline void split1(float v, short& h, short& m, short& l) {
  float fh = bf_round(v, h);
  float r = v - fh;
  float fm = bf_round(r, m);
  float r2 = r - fm;  // <= 8 significant bits -> exact in bf16
  __hip_bfloat16 b = __float2bfloat16(r2);
  __builtin_memcpy(&l, &b, 2);
}

// Packed 2-at-a-time bf16 convert (1 VALU op; packing matches frag word layout)
__device__ inline uint32_t cvtpk(float lo, float hi) {
  uint32_t r;
  asm("v_cvt_pk_bf16_f32 %0, %1, %2" : "=v"(r) : "v"(lo), "v"(hi));
  return r;
}
// Exact 3-way split of 8 consecutive-k f32 into 3 packed bf16x8 frags
__device__ inline void split8(float4 q0, float4 q1, short8& ah, short8& am, short8& al) {
  float f[8] = {q0.x, q0.y, q0.z, q0.w, q1.x, q1.y, q1.z, q1.w};
  uint32_t H[4], M[4], L[4];
#pragma unroll
  for (int p = 0; p < 4; ++p) {
    float v0 = f[2 * p], v1 = f[2 * p + 1];
    uint32_t h = cvtpk(v0, v1);
    float r0 = v0 - __uint_as_float(h << 16);
    float r1 = v1 - __uint_as_float(h & 0xffff0000u);
    uint32_t m = cvtpk(r0, r1);
    float s0 = r0 - __uint_as_float(m << 16);
    float s1 = r1 - __uint_as_float(m & 0xffff0000u);
    uint32_t lw = cvtpk(s0, s1);  // residual has <=8 mantissa bits: exact
    H[p] = h; M[p] = m; L[p] = lw;
  }
  __builtin_memcpy(&ah, H, 16);
  __builtin_memcpy(&am, M, 16);
  __builtin_memcpy(&al, L, 16);
}

// ---------------------------------------------------------------------------
// Prep (one launch): transpose WrT/W2T/WpT + split W_in into 3 bf16 planes
// B3 layout: [plane][c][704], k-padded with zeros
// ---------------------------------------------------------------------------
__global__ void k_prep(const float* __restrict__ Wr, const float* __restrict__ W2,
                       const float* __restrict__ Wp, const float* __restrict__ Win,
                       float* __restrict__ WrT, float* __restrict__ W2T,
                       float* __restrict__ WpT, ushort* __restrict__ B3) {
  int idx = blockIdx.x * blockDim.x + threadIdx.x;
  if (idx < 3 * 16384) {
    int sel = idx >> 14;
    int r = idx & 16383;
    int j = r >> 7, c = r & 127;
    const float* src = (sel == 0) ? Wr : (sel == 1) ? W2 : Wp;
    float* dst = (sel == 0) ? WrT : (sel == 1) ? W2T : WpT;
    dst[r] = src[c * 128 + j];
  } else {
    int i2 = idx - 49152;
    if (i2 >= 128 * 704) return;
    int c = i2 / 704, d = i2 - c * 704;
    float v = (d < 700) ? Win[c * 700 + d] : 0.f;
    short h, m, l;
    split1(v, h, m, l);
    B3[i2] = (ushort)h;
    B3[90112 + i2] = (ushort)m;
    B3[180224 + i2] = (ushort)l;
  }
}

// ---------------------------------------------------------------------------
// GEMM1 via split-bf16 6-product MFMA (fp32-grade, spike-exact), 32x32x16:
//   XW[m][c] = x_row(m) . W_in[c] + b_in[c] + b_rec[c],  m = t*4096+n
// 128x128 tile, BK=32, 512 blocks x 512 threads.
// Wave grid 2(row)x2(col)x2(k-half): wave owns 64 rows x 64 cols x k16,
// acc[2][2] f32x16. Split-VALU and LDS-read redundancy halved vs 2x4 grid;
// k-halves reduced cross-wave through LDS in the epilogue (one-time).
// A staged f32 (row-XOR source swizzle); B staged bf16x3 (chunk-XOR).
// Double-buffered 80 KB -> 2 blocks/CU.
// ---------------------------------------------------------------------------
__global__ __launch_bounds__(512, 4) void k_gemm_mfma(
    const float* __restrict__ x, const ushort* __restrict__ Bs3,
    const float* __restrict__ b_in, const float* __restrict__ b_rec,
    float* __restrict__ XW) {
  __shared__ __align__(16) char lds[81920];  // 2 bufs x (A 16K f32 | B 24K bf16x3)

  const int tid = threadIdx.x;
  const int w = tid >> 6;      // 0..7
  const int l = tid & 63;
  const int blk = blockIdx.x;
  const int ks = w >> 2;       // 0..1  k-half (16 of BK=32)
  const int wc = (w >> 1) & 1; // 0..1  col half (64 cols)
  const int wr = w & 1;        // 0..1  row half (64 rows)

  // --- A staging: 16 gload16/kt, wave does 2. Row swizzle on source:
  // LDS slot (row, cp) holds global chunk cp^(row&7); row&7 == l>>3.
  const int jA = (((l & 7) ^ (l >> 3)) * 4);  // source k-offset (elements)
  const int t_blk = (blk * 128) >> 12;
  const int n0_blk = (blk * 128) & 4095;
  int arow[2];
#pragma unroll
  for (int i = 0; i < 2; ++i) {
    int m = (w * 2 + i) * 8 + (l >> 3);
    arow[i] = ((n0_blk + m) * 16 + t_blk) * 700;
  }
  // --- B staging: 24 gload16/kt (3 planes x 8 col-groups of 16), wave does 3.
  // LDS: plane*8192 + col*64 + cp*16; slot cp holds global chunk cp^((col>>1)&3).
  const ushort* bsrc[3];
  int bdst[3];
#pragma unroll
  for (int i = 0; i < 3; ++i) {
    int idx = w * 3 + i;
    int plane = idx >> 3, cg = idx & 7;
    int col = cg * 16 + (l >> 2);
    bsrc[i] = Bs3 + plane * 90112 + col * 704 + (((l & 3) ^ ((l >> 3) & 3)) * 8);
    bdst[i] = 16384 + plane * 8192 + cg * 1024;
  }
  const int adst = (w * 2) * 1024;

  // --- fragment read constants (32x32x16: lane&31 = row/col, lane>>5 = k-sub)
  const int lc = l & 31, lk = l >> 5;
  const int akey = lc & 7;           // A row-swizzle key
  const int bkey = (lc >> 1) & 3;    // B col-swizzle key
  const int c0 = ks * 4 + lk * 2;    // A f32 16B-chunk base for this wave's k16
  const int bchunk = ks * 2 + lk;    // B bf16 16B-chunk
  int aoffb[2];
#pragma unroll
  for (int rt = 0; rt < 2; ++rt) aoffb[rt] = (wr * 64 + rt * 32 + lc) * 128;
  int boffb[2];
  float bias[2];
#pragma unroll
  for (int ct = 0; ct < 2; ++ct) {
    int col = wc * 64 + ct * 32 + lc;
    boffb[ct] = 16384 + col * 64 + ((bchunk ^ bkey) * 16);
    bias[ct] = b_in[col] + b_rec[col];
  }

  f32x16 acc[2][2];
#pragma unroll
  for (int i = 0; i < 2; ++i)
#pragma unroll
    for (int j = 0; j < 2; ++j)
#pragma unroll
      for (int r = 0; r < 16; ++r) acc[i][j][r] = 0.f;

  auto STAGE = [&](int buf, int kt) {  // 5 gload_lds per wave
    const int k0 = kt * 32;
    char* base = lds + buf * 40960;
#pragma unroll
    for (int i = 0; i < 2; ++i) {
      int k = k0 + jA;
      int off = (k < 700) ? (arow[i] + k) : 0;  // pad region: B plane is zero
      gload16(x + off, base + adst + i * 1024);
    }
#pragma unroll
    for (int i = 0; i < 3; ++i)
      gload16(bsrc[i] + k0, base + bdst[i]);
  };

  STAGE(0, 0);
  __syncthreads();
  int buf = 0;
  for (int kt = 0; kt < 22; ++kt) {
    if (kt + 1 < 22) STAGE(buf ^ 1, kt + 1);
    const char* base = lds + buf * 40960;
    // B fragments for this wave's k16 (held across rt)
    short8 bh0, bm0, bl0, bh1, bm1, bl1;
    {
      const char* bb0 = base + boffb[0];
      bh0 = *(const short8*)(bb0);
      bm0 = *(const short8*)(bb0 + 8192);
      bl0 = *(const short8*)(bb0 + 16384);
      const char* bb1 = base + boffb[1];
      bh1 = *(const short8*)(bb1);
      bm1 = *(const short8*)(bb1 + 8192);
      bl1 = *(const short8*)(bb1 + 16384);
    }
#pragma unroll
    for (int rt = 0; rt < 2; ++rt) {
      const char* ab = base + aoffb[rt];
      float4 q0 = *(const float4*)(ab + ((c0) ^ akey) * 16);
      float4 q1 = *(const float4*)(ab + ((c0 + 1) ^ akey) * 16);
      short8 ah, am, al;
      split8(q0, q1, ah, am, al);
      __builtin_amdgcn_s_setprio(1);
      acc[rt][0] = MFMA32(ah, bh0, acc[rt][0]);
      acc[rt][0] = MFMA32(am, bh0, acc[rt][0]);
      acc[rt][0] = MFMA32(ah, bm0, acc[rt][0]);
      acc[rt][0] = MFMA32(am, bm0, acc[rt][0]);
      acc[rt][0] = MFMA32(al, bh0, acc[rt][0]);
      acc[rt][0] = MFMA32(ah, bl0, acc[rt][0]);
      acc[rt][1] = MFMA32(ah, bh1, acc[rt][1]);
      acc[rt][1] = MFMA32(am, bh1, acc[rt][1]);
      acc[rt][1] = MFMA32(ah, bm1, acc[rt][1]);
      acc[rt][1] = MFMA32(am, bm1, acc[rt][1]);
      acc[rt][1] = MFMA32(al, bh1, acc[rt][1]);
      acc[rt][1] = MFMA32(ah, bl1, acc[rt][1]);
      __builtin_amdgcn_s_setprio(0);
    }
    __syncthreads();
    buf ^= 1;
  }

  // --- Epilogue: cross-wave k-half reduce through LDS, then store.
  // Region (p, h) at (p*2+h)*8192, p = wc*2+wr; slot layout (ct*4+j)*1024 + l*16
  // (lane-major 16B, linear -> conflict-free). ks=1 writes its rt=0 partials to
  // h=0; ks=0 writes rt=1 to h=1. After barrier each wave finishes rt==ks.
  const int p2 = (wc * 2 + wr) * 2;
  if (ks == 0) {
    char* wreg = lds + (p2 + 1) * 8192;
#pragma unroll
    for (int ct = 0; ct < 2; ++ct)
#pragma unroll
      for (int j = 0; j < 4; ++j) {
        f32x4 v = {acc[1][ct][4 * j], acc[1][ct][4 * j + 1],
                   acc[1][ct][4 * j + 2], acc[1][ct][4 * j + 3]};
        *(f32x4*)(wreg + (ct * 4 + j) * 1024 + l * 16) = v;
      }
  } else {
    char* wreg = lds + (p2 + 0) * 8192;
#pragma unroll
    for (int ct = 0; ct < 2; ++ct)
#pragma unroll
      for (int j = 0; j < 4; ++j) {
        f32x4 v = {acc[0][ct][4 * j], acc[0][ct][4 * j + 1],
                   acc[0][ct][4 * j + 2], acc[0][ct][4 * j + 3]};
        *(f32x4*)(wreg + (ct * 4 + j) * 1024 + l * 16) = v;
      }
  }
  __syncthreads();
  {
    const char* rreg = lds + (p2 + ks) * 8192;
    const int rowb = blk * 128 + wr * 64 + ks * 32 + 4 * lk;
    // C/D layout: col=lane&31, row=(reg&3)+8*(reg>>2)+4*(lane>>5)  (m74/m101)
    if (ks == 0) {
#pragma unroll
      for (int ct = 0; ct < 2; ++ct) {
        const int col = wc * 64 + ct * 32 + lc;
#pragma unroll
        for (int j = 0; j < 4; ++j) {
          f32x4 part = *(const f32x4*)(rreg + (ct * 4 + j) * 1024 + l * 16);
#pragma unroll
          for (int r = 0; r < 4; ++r) {
            int mrow = rowb + r + 8 * j;
            XW[(size_t)mrow * 128 + col] = acc[0][ct][4 * j + r] + part[r] + bias[ct];
          }
        }
      }
    } else {
#pragma unroll
      for (int ct = 0; ct < 2; ++ct) {
        const int col = wc * 64 + ct * 32 + lc;
#pragma unroll
        for (int j = 0; j < 4; ++j) {
          f32x4 part = *(const f32x4*)(rreg + (ct * 4 + j) * 1024 + l * 16);
#pragma unroll
          for (int r = 0; r < 4; ++r) {
            int mrow = rowb + r + 8 * j;
            XW[(size_t)mrow * 128 + col] = acc[1][ct][4 * j + r] + part[r] + bias[ct];
          }
        }
      }
    }
  }
}

// ---------------------------------------------------------------------------
// Fused scan: LIF layer1+2 (recurrent), attention maps, attended, LIF layer3,
// and the 20-class projection. Block = 2 rows x 128 channels. Features kept
// in LDS as bitmasks; channel-means are exact popcounts.
// ---------------------------------------------------------------------------
__global__ __launch_bounds__(256) void k_scan(
    const float* __restrict__ XW, const float* __restrict__ WrT,
    const float* __restrict__ W2T, const float* __restrict__ b2,
    const float* __restrict__ WpT, const float* __restrict__ b_p,
    const float* __restrict__ W_out, const float* __restrict__ b_out,
    const float* __restrict__ k_t, const float* __restrict__ k_c,
    float* __restrict__ features, float* __restrict__ attended,
    float* __restrict__ out0) {
  const int tid = threadIdx.x;
  const int r = tid >> 7;          // row within block
  const int c = tid & 127;         // channel
  const int n = blockIdx.x * 2 + r;
  const int wv = c >> 6;           // wave-half within row
  const int lane = tid & 63;

  __shared__ u64 smask[2][2];
  __shared__ u64 fmask[2][16][2];
  __shared__ float m0p[2][130];    // mean0 padded for c_att conv
  __shared__ float ta[2][16];
  __shared__ float ca[2][128];
  __shared__ float g[2][128];

  if (tid < 4) ((u64*)smask)[tid] = 0ull;
  float v1 = 0.f, v2 = 0.f, fsum = 0.f;
  const float b2c = b2[c];
  __syncthreads();

  // ---- phase 1: recurrent LIF scan ----
  for (int t = 0; t < 16; ++t) {
    float inp = XW[(size_t)((t << 12) | n) * 128 + c];
    u64 p0 = smask[r][0], p1 = smask[r][1];   // spikes_last (uniform per row)
    while (p0) { int j = __builtin_ctzll(p0); p0 &= p0 - 1; inp += WrT[j * 128 + c]; }
    while (p1) { int j = __builtin_ctzll(p1); p1 &= p1 - 1; inp += WrT[(64 + j) * 128 + c]; }
    v1 = v1 + (inp - v1) * 0.5f;            // decay_input=True, TAU=2
    bool s1 = (v1 - 1.0f) >= 0.f;
    v1 = s1 ? 0.f : v1;
    __syncthreads();                        // everyone done reading old smask
    u64 bm = __ballot((int)s1);
    if (lane == 0) smask[r][wv] = bm;
    __syncthreads();
    float x2 = b2c;
    u64 q0 = smask[r][0], q1 = smask[r][1];
    while (q0) { int j = __builtin_ctzll(q0); q0 &= q0 - 1; x2 += W2T[j * 128 + c]; }
    while (q1) { int j = __builtin_ctzll(q1); q1 &= q1 - 1; x2 += W2T[(64 + j) * 128 + c]; }
    v2 = v2 + (x2 - v2) * 0.5f;
    bool f = (v2 - 1.0f) >= 0.f;
    v2 = f ? 0.f : v2;
    float ff = f ? 1.f : 0.f;
    features[(size_t)((t << 12) | n) * 128 + c] = ff;
    fsum += ff;
    u64 fb = __ballot((int)f);
    if (lane == 0) fmask[r][t][wv] = fb;
  }

  // mean0 (exact: integer sums, pow2 divides)
  m0p[r][c + 1] = fsum * (1.f / 16.f);
  if (c == 0) { m0p[r][0] = 0.f; m0p[r][129] = 0.f; }
  __syncthreads();  // fmask + m0p complete

  // t_att: conv over T (SAME, width 3) of channel-means, + sigmoid
  if (c < 16) {
    float acc = 0.f;
#pragma unroll
    for (int j = 0; j < 3; ++j) {
      int tt = c - 1 + j;
      if (tt >= 0 && tt < 16) {
        float m = (float)(__popcll(fmask[r][tt][0]) + __popcll(fmask[r][tt][1])) * (1.f / 128.f);
        acc += k_t[j] * m;
      }
    }
    ta[r][c] = 1.f / (1.f + expf(-acc));
  }
  // c_att: conv over C (SAME, width 3) of time-means, + sigmoid
  {
    float acc = k_c[0] * m0p[r][c] + k_c[1] * m0p[r][c + 1] + k_c[2] * m0p[r][c + 2];
    ca[r][c] = 1.f / (1.f + expf(-acc));
  }
  __syncthreads();

  // ---- phase 2: attended + LIF layer3 + spike-count (no syncs needed) ----
  float v3 = 0.f, ssum = 0.f;
  const float bpc = b_p[c];
  const float cac = ca[r][c];
  for (int t = 0; t < 16; ++t) {
    u64 m0 = fmask[r][t][0], m1 = fmask[r][t][1];
    float tat = ta[r][t];
    bool bit = ((wv ? m1 : m0) >> (c & 63)) & 1;
    float att = bit ? tat * cac : 0.f;      // feat in {0,1}: (feat*ta)*ca
    attended[(size_t)((t << 12) | n) * 128 + c] = att;
    float h = bpc;
    while (m0) { int j = __builtin_ctzll(m0); m0 &= m0 - 1; h += (tat * ca[r][j]) * WpT[j * 128 + c]; }
    while (m1) { int j = __builtin_ctzll(m1); m1 &= m1 - 1; h += (tat * ca[r][64 + j]) * WpT[(64 + j) * 128 + c]; }
    v3 = v3 + (h - v3) * 0.5f;
    bool s = (v3 - 1.0f) >= 0.f;
    v3 = s ? 0.f : v3;
    ssum += s ? 1.f : 0.f;
  }
  g[r][c] = ssum * (1.f / 16.f);
  __syncthreads();
  if (c < 20) {
    float acc = b_out[c];
    for (int j = 0; j < 128; ++j) acc += g[r][j] * W_out[c * 128 + j];
    out0[n * 20 + c] = acc;
  }
}

// ---------------------------------------------------------------------------
extern "C" void kernel_launch(void* const* d_in, const int* in_sizes, int n_in,
                              void* d_out, int out_size, void* d_ws, size_t ws_size,
                              hipStream_t stream) {
  const float* x     = (const float*)d_in[0];
  const float* W_in  = (const float*)d_in[1];
  const float* b_in  = (const float*)d_in[2];
  const float* W_rec = (const float*)d_in[3];
  const float* b_rec = (const float*)d_in[4];
  const float* W2    = (const float*)d_in[5];
  const float* b2    = (const float*)d_in[6];
  const float* k_t   = (const float*)d_in[7];
  const float* k_c   = (const float*)d_in[8];
  const float* W_p   = (const float*)d_in[9];
  const float* b_p   = (const float*)d_in[10];
  const float* W_out = (const float*)d_in[11];
  const float* b_out = (const float*)d_in[12];

  float* out      = (float*)d_out;
  float* out0     = out;                        // [4096,20]
  float* features = out + 81920;                // [16,4096,128]
  float* attended = out + 81920 + 8388608;      // [16,4096,128]
  float* XW       = attended;                   // staged here, overwritten by scan

  float* ws  = (float*)d_ws;
  float* WrT = ws;                  // 16384 f32
  float* W2T = ws + 16384;          // 16384 f32
  float* WpT = ws + 32768;          // 16384 f32
  ushort* B3 = (ushort*)(ws + 49152);  // 3 x 128 x 704 bf16 = 540 KB

  hipLaunchKernelGGL(k_prep, dim3(544), dim3(256), 0, stream,
                     W_rec, W2, W_p, W_in, WrT, W2T, WpT, B3);
  hipLaunchKernelGGL(k_gemm_mfma, dim3(512), dim3(512), 0, stream,
                     x, B3, b_in, b_rec, XW);
  hipLaunchKernelGGL(k_scan, dim3(2048), dim3(256), 0, stream,
                     XW, WrT, W2T, b2, WpT, b_p, W_out, b_out, k_t, k_c,
                     features, attended, out0);
}

// Round 8
// 92.986 us; speedup vs baseline: 1.2127x; 1.2127x over previous
//
#include <hip/hip_runtime.h>
#include <hip/hip_bf16.h>
#include <stdint.h>

// Problem constants: N=4096, T=16, D=700 (pad 704), C=128, NC=20
// Output layout (f32): out0 [4096,20] | features [16,4096,128] | attended [16,4096,128]

typedef __attribute__((ext_vector_type(8))) _Float16 half8;  // f16x8 MFMA frag
typedef __attribute__((ext_vector_type(4))) float f32x4;
typedef unsigned long long u64;

#define MFMA16F(a, b, c) __builtin_amdgcn_mfma_f32_16x16x32_f16(a, b, c, 0, 0, 0)

__device__ inline void gload16(const void* g, void* l) {
  __builtin_amdgcn_global_load_lds(
      (const __attribute__((address_space(1))) uint32_t*)g,
      (__attribute__((address_space(3))) uint32_t*)l, 16, 0, 0);
}

// ---------------------------------------------------------------------------
// f16 2-plane split with subnormal-avoiding scales:
//   a = h*2^-4 + l*2^-15 + ra,  |ra| <= 2^-24|a|   (RNE both planes)
// All stored values are normal-range f16 for |a| in [1e-4, 91].
// ---------------------------------------------------------------------------
__device__ inline void splitf16(float4 q0, float4 q1, half8& hh, half8& ll) {
  float f[8] = {q0.x, q0.y, q0.z, q0.w, q1.x, q1.y, q1.z, q1.w};
  _Float16 H[8], L[8];
#pragma unroll
  for (int j = 0; j < 8; ++j) {
    _Float16 h1 = (_Float16)(f[j] * 16.0f);          // RNE
    float r = fmaf((float)h1, -0.0625f, f[j]);       // exact residual
    L[j] = (_Float16)(r * 32768.0f);                 // 2^15, RNE
    H[j] = h1;
  }
  __builtin_memcpy(&hh, H, 16);
  __builtin_memcpy(&ll, L, 16);
}

// ---------------------------------------------------------------------------
// Prep (one launch): transpose WrT/W2T/WpT + split W_in into 2 f16 planes
// F2 layout: [plane][c][704] f16-bits, k-padded zeros.
//   b = p1*2^-8 + p2*2^-19 + rb, |rb| <= 2^-24|b|
// ---------------------------------------------------------------------------
__global__ void k_prep(const float* __restrict__ Wr, const float* __restrict__ W2,
                       const float* __restrict__ Wp, const float* __restrict__ Win,
                       float* __restrict__ WrT, float* __restrict__ W2T,
                       float* __restrict__ WpT, ushort* __restrict__ F2) {
  int idx = blockIdx.x * blockDim.x + threadIdx.x;
  if (idx < 3 * 16384) {
    int sel = idx >> 14;
    int r = idx & 16383;
    int j = r >> 7, c = r & 127;
    const float* src = (sel == 0) ? Wr : (sel == 1) ? W2 : Wp;
    float* dst = (sel == 0) ? WrT : (sel == 1) ? W2T : WpT;
    dst[r] = src[c * 128 + j];
  } else {
    int i2 = idx - 49152;
    if (i2 >= 128 * 704) return;
    int c = i2 / 704, d = i2 - c * 704;
    float w = (d < 700) ? Win[c * 700 + d] : 0.f;
    _Float16 b1 = (_Float16)(w * 256.0f);            // RNE, scale 2^8
    float r = fmaf((float)b1, -0.00390625f, w);      // exact residual
    _Float16 b2 = (_Float16)(r * 524288.0f);         // scale 2^19, RNE
    ushort u1, u2;
    __builtin_memcpy(&u1, &b1, 2);
    __builtin_memcpy(&u2, &b2, 2);
    F2[i2] = u1;
    F2[90112 + i2] = u2;
  }
}

// ---------------------------------------------------------------------------
// GEMM1 via f16 2-plane 3-product MFMA (fp32-grade, spike-safe):
//   XW[m][c] = x_row(m) . W_in[c] + b_in[c] + b_rec[c],  m = t*4096+n
// Products kept: a1b1 (acc_h, scale 2^-12), a1b2 + a2b1 (acc_m, scale 2^-23).
// Dropped a2b2 ~ 2^-22|ab| (RMS ~2e-7/dot; far below output compare unit).
// R3 skeleton: 128x128 tile, BK=32, 512 blocks x 512 threads, wave grid
// 2(row-64)x4(col-32), mf=4/nf=2, dbuf 64 KB -> 2 blocks/CU, 1 barrier/kt.
// A staged f32 (row-XOR source swizzle); B staged f16x2 (chunk-XOR).
// ---------------------------------------------------------------------------
__global__ __launch_bounds__(512, 4) void k_gemm_mfma(
    const float* __restrict__ x, const ushort* __restrict__ F2,
    const float* __restrict__ b_in, const float* __restrict__ b_rec,
    float* __restrict__ XW) {
  __shared__ __align__(16) char lds[65536];  // 2 bufs x (A 16K f32 | B 16K f16x2)

  const int tid = threadIdx.x;
  const int w = tid >> 6;      // 0..7
  const int l = tid & 63;
  const int blk = blockIdx.x;
  const int wr = w >> 2;       // 0..1  (row group of 64)
  const int wc = w & 3;        // 0..3  (col group of 32)

  // --- A staging: 16 gload16/kt, wave does 2. Row swizzle on source:
  // LDS slot (row, cp) holds global chunk cp^(row&7); row&7 == l>>3.
  const int jA = (((l & 7) ^ (l >> 3)) * 4);  // source k-offset (elements)
  const int t_blk = (blk * 128) >> 12;
  const int n0_blk = (blk * 128) & 4095;
  int arow[2];
#pragma unroll
  for (int i = 0; i < 2; ++i) {
    int m = (w * 2 + i) * 8 + (l >> 3);
    arow[i] = ((n0_blk + m) * 16 + t_blk) * 700;
  }
  // --- B staging: 16 gload16/kt (2 planes x 8 col-groups of 16), wave does 2.
  // LDS: 16384 + plane*8192 + col*64 + cp*16; slot cp holds chunk cp^((col>>1)&3).
  const ushort* bsrc[2];
  int bdst[2];
#pragma unroll
  for (int i = 0; i < 2; ++i) {
    int idx = w * 2 + i;
    int plane = idx >> 3, cg = idx & 7;
    int col = cg * 16 + (l >> 2);
    bsrc[i] = F2 + plane * 90112 + col * 704 + (((l & 3) ^ ((l >> 3) & 3)) * 8);
    bdst[i] = 16384 + plane * 8192 + cg * 1024;
  }
  const int adst = (w * 2) * 1024;

  // --- fragment read constants ---
  const int lm = l & 15, kh = l >> 4;
  const int p0 = ((2 * kh) ^ (lm & 7)) * 16;      // A chunk swizzle
  const int p1 = ((2 * kh + 1) ^ (lm & 7)) * 16;
  const int bswz = (kh ^ ((lm >> 1) & 3)) * 16;   // B chunk swizzle
  int aoff[4], boff[2];
#pragma unroll
  for (int mf = 0; mf < 4; ++mf) aoff[mf] = (wr * 64 + mf * 16 + lm) * 128;
#pragma unroll
  for (int nf = 0; nf < 2; ++nf) boff[nf] = 16384 + (wc * 32 + nf * 16 + lm) * 64 + bswz;

  f32x4 acc_h[4][2], acc_m[4][2];
#pragma unroll
  for (int i = 0; i < 4; ++i)
#pragma unroll
    for (int j = 0; j < 2; ++j) {
      acc_h[i][j] = (f32x4){0.f, 0.f, 0.f, 0.f};
      acc_m[i][j] = (f32x4){0.f, 0.f, 0.f, 0.f};
    }

  auto STAGE = [&](int buf, int kt) {  // 4 gload_lds per wave
    const int k0 = kt * 32;
    char* base = lds + buf * 32768;
#pragma unroll
    for (int i = 0; i < 2; ++i) {
      int k = k0 + jA;
      int off = (k < 700) ? (arow[i] + k) : 0;  // pad region: B plane is zero
      gload16(x + off, base + adst + i * 1024);
    }
#pragma unroll
    for (int i = 0; i < 2; ++i)
      gload16(bsrc[i] + k0, base + bdst[i]);
  };

  STAGE(0, 0);
  __syncthreads();
  int buf = 0;
  for (int kt = 0; kt < 22; ++kt) {
    if (kt + 1 < 22) STAGE(buf ^ 1, kt + 1);
    const char* base = lds + buf * 32768;
    // B fragments (held across mf)
    half8 b1[2], b2[2];
#pragma unroll
    for (int nf = 0; nf < 2; ++nf) {
      const char* bb = base + boff[nf];
      b1[nf] = *(const half8*)(bb);
      b2[nf] = *(const half8*)(bb + 8192);
    }
#pragma unroll
    for (int mf = 0; mf < 4; ++mf) {
      const char* ab = base + aoff[mf];
      float4 q0 = *(const float4*)(ab + p0);
      float4 q1 = *(const float4*)(ab + p1);
      half8 a1, a2;
      splitf16(q0, q1, a1, a2);
#pragma unroll
      for (int nf = 0; nf < 2; ++nf) {
        acc_h[mf][nf] = MFMA16F(a1, b1[nf], acc_h[mf][nf]);
        acc_m[mf][nf] = MFMA16F(a1, b2[nf], acc_m[mf][nf]);
        acc_m[mf][nf] = MFMA16F(a2, b1[nf], acc_m[mf][nf]);
      }
    }
    __syncthreads();
    buf ^= 1;
  }

  // Epilogue: C/D layout col=lane&15, row=(lane>>4)*4+r (m89-verified).
  // XW = acc_h*2^-12 + acc_m*2^-23 + bias.
  const int outbase = blk * 128;
#pragma unroll
  for (int nf = 0; nf < 2; ++nf) {
    int col = wc * 32 + nf * 16 + lm;
    float bias = b_in[col] + b_rec[col];
#pragma unroll
    for (int mf = 0; mf < 4; ++mf) {
      int mrow = outbase + wr * 64 + mf * 16 + kh * 4;
#pragma unroll
      for (int r = 0; r < 4; ++r)
        XW[(size_t)(mrow + r) * 128 + col] =
            acc_h[mf][nf][r] * 0.000244140625f +
            acc_m[mf][nf][r] * 1.1920928955078125e-7f + bias;
    }
  }
}

// ---------------------------------------------------------------------------
// Fused scan: LIF layer1+2 (recurrent), attention maps, attended, LIF layer3,
// and the 20-class projection. Block = 2 rows x 128 channels. Features kept
// in LDS as bitmasks; channel-means are exact popcounts.
// ---------------------------------------------------------------------------
__global__ __launch_bounds__(256) void k_scan(
    const float* __restrict__ XW, const float* __restrict__ WrT,
    const float* __restrict__ W2T, const float* __restrict__ b2,
    const float* __restrict__ WpT, const float* __restrict__ b_p,
    const float* __restrict__ W_out, const float* __restrict__ b_out,
    const float* __restrict__ k_t, const float* __restrict__ k_c,
    float* __restrict__ features, float* __restrict__ attended,
    float* __restrict__ out0) {
  const int tid = threadIdx.x;
  const int r = tid >> 7;          // row within block
  const int c = tid & 127;         // channel
  const int n = blockIdx.x * 2 + r;
  const int wv = c >> 6;           // wave-half within row
  const int lane = tid & 63;

  __shared__ u64 smask[2][2];
  __shared__ u64 fmask[2][16][2];
  __shared__ float m0p[2][130];    // mean0 padded for c_att conv
  __shared__ float ta[2][16];
  __shared__ float ca[2][128];
  __shared__ float g[2][128];

  if (tid < 4) ((u64*)smask)[tid] = 0ull;
  float v1 = 0.f, v2 = 0.f, fsum = 0.f;
  const float b2c = b2[c];
  __syncthreads();

  // ---- phase 1: recurrent LIF scan ----
  for (int t = 0; t < 16; ++t) {
    float inp = XW[(size_t)((t << 12) | n) * 128 + c];
    u64 p0 = smask[r][0], p1 = smask[r][1];   // spikes_last (uniform per row)
    while (p0) { int j = __builtin_ctzll(p0); p0 &= p0 - 1; inp += WrT[j * 128 + c]; }
    while (p1) { int j = __builtin_ctzll(p1); p1 &= p1 - 1; inp += WrT[(64 + j) * 128 + c]; }
    v1 = v1 + (inp - v1) * 0.5f;            // decay_input=True, TAU=2
    bool s1 = (v1 - 1.0f) >= 0.f;
    v1 = s1 ? 0.f : v1;
    __syncthreads();                        // everyone done reading old smask
    u64 bm = __ballot((int)s1);
    if (lane == 0) smask[r][wv] = bm;
    __syncthreads();
    float x2 = b2c;
    u64 q0 = smask[r][0], q1 = smask[r][1];
    while (q0) { int j = __builtin_ctzll(q0); q0 &= q0 - 1; x2 += W2T[j * 128 + c]; }
    while (q1) { int j = __builtin_ctzll(q1); q1 &= q1 - 1; x2 += W2T[(64 + j) * 128 + c]; }
    v2 = v2 + (x2 - v2) * 0.5f;
    bool f = (v2 - 1.0f) >= 0.f;
    v2 = f ? 0.f : v2;
    float ff = f ? 1.f : 0.f;
    features[(size_t)((t << 12) | n) * 128 + c] = ff;
    fsum += ff;
    u64 fb = __ballot((int)f);
    if (lane == 0) fmask[r][t][wv] = fb;
  }

  // mean0 (exact: integer sums, pow2 divides)
  m0p[r][c + 1] = fsum * (1.f / 16.f);
  if (c == 0) { m0p[r][0] = 0.f; m0p[r][129] = 0.f; }
  __syncthreads();  // fmask + m0p complete

  // t_att: conv over T (SAME, width 3) of channel-means, + sigmoid
  if (c < 16) {
    float acc = 0.f;
#pragma unroll
    for (int j = 0; j < 3; ++j) {
      int tt = c - 1 + j;
      if (tt >= 0 && tt < 16) {
        float m = (float)(__popcll(fmask[r][tt][0]) + __popcll(fmask[r][tt][1])) * (1.f / 128.f);
        acc += k_t[j] * m;
      }
    }
    ta[r][c] = 1.f / (1.f + expf(-acc));
  }
  // c_att: conv over C (SAME, width 3) of time-means, + sigmoid
  {
    float acc = k_c[0] * m0p[r][c] + k_c[1] * m0p[r][c + 1] + k_c[2] * m0p[r][c + 2];
    ca[r][c] = 1.f / (1.f + expf(-acc));
  }
  __syncthreads();

  // ---- phase 2: attended + LIF layer3 + spike-count (no syncs needed) ----
  float v3 = 0.f, ssum = 0.f;
  const float bpc = b_p[c];
  const float cac = ca[r][c];
  for (int t = 0; t < 16; ++t) {
    u64 m0 = fmask[r][t][0], m1 = fmask[r][t][1];
    float tat = ta[r][t];
    bool bit = ((wv ? m1 : m0) >> (c & 63)) & 1;
    float att = bit ? tat * cac : 0.f;      // feat in {0,1}: (feat*ta)*ca
    attended[(size_t)((t << 12) | n) * 128 + c] = att;
    float h = bpc;
    while (m0) { int j = __builtin_ctzll(m0); m0 &= m0 - 1; h += (tat * ca[r][j]) * WpT[j * 128 + c]; }
    while (m1) { int j = __builtin_ctzll(m1); m1 &= m1 - 1; h += (tat * ca[r][64 + j]) * WpT[(64 + j) * 128 + c]; }
    v3 = v3 + (h - v3) * 0.5f;
    bool s = (v3 - 1.0f) >= 0.f;
    v3 = s ? 0.f : v3;
    ssum += s ? 1.f : 0.f;
  }
  g[r][c] = ssum * (1.f / 16.f);
  __syncthreads();
  if (c < 20) {
    float acc = b_out[c];
    for (int j = 0; j < 128; ++j) acc += g[r][j] * W_out[c * 128 + j];
    out0[n * 20 + c] = acc;
  }
}

// ---------------------------------------------------------------------------
extern "C" void kernel_launch(void* const* d_in, const int* in_sizes, int n_in,
                              void* d_out, int out_size, void* d_ws, size_t ws_size,
                              hipStream_t stream) {
  const float* x     = (const float*)d_in[0];
  const float* W_in  = (const float*)d_in[1];
  const float* b_in  = (const float*)d_in[2];
  const float* W_rec = (const float*)d_in[3];
  const float* b_rec = (const float*)d_in[4];
  const float* W2    = (const float*)d_in[5];
  const float* b2    = (const float*)d_in[6];
  const float* k_t   = (const float*)d_in[7];
  const float* k_c   = (const float*)d_in[8];
  const float* W_p   = (const float*)d_in[9];
  const float* b_p   = (const float*)d_in[10];
  const float* W_out = (const float*)d_in[11];
  const float* b_out = (const float*)d_in[12];

  float* out      = (float*)d_out;
  float* out0     = out;                        // [4096,20]
  float* features = out + 81920;                // [16,4096,128]
  float* attended = out + 81920 + 8388608;      // [16,4096,128]
  float* XW       = attended;                   // staged here, overwritten by scan

  float* ws  = (float*)d_ws;
  float* WrT = ws;                  // 16384 f32
  float* W2T = ws + 16384;          // 16384 f32
  float* WpT = ws + 32768;          // 16384 f32
  ushort* F2 = (ushort*)(ws + 49152);  // 2 x 128 x 704 f16 = 360 KB

  hipLaunchKernelGGL(k_prep, dim3(544), dim3(256), 0, stream,
                     W_rec, W2, W_p, W_in, WrT, W2T, WpT, F2);
  hipLaunchKernelGGL(k_gemm_mfma, dim3(512), dim3(512), 0, stream,
                     x, F2, b_in, b_rec, XW);
  hipLaunchKernelGGL(k_scan, dim3(2048), dim3(256), 0, stream,
                     XW, WrT, W2T, b2, WpT, b_p, W_out, b_out, k_t, k_c,
                     features, attended, out0);
}